// Round 15
// baseline (504.402 us; speedup 1.0000x reference)
//
#include <hip/hip_runtime.h>
#include <hip/hip_fp16.h>

// Heston Euler-Maruyama: 100000 paths x 512 steps, fp32. Single kernel.
// PAGE-GRANULAR reads AND writes + 3-wave in-block pipeline (1 block/CU):
//   - block owns 392 consecutive paths = ~10 groups of 40; slot = (group,
//     quarter of 128 steps)
//   - wave 0: loads next slot's z into LDS as 40 instrs x (64 lanes x 16B)
//     = 1KB CONTIGUOUS per z-row visit (was 128B/visit in R0-R13)
//   - wave 1: simulates 40 paths x 128 steps from LDS z, packs fp16
//     (cvt_pkrtz) into out tile
//   - wave 2: stores previous slot via R12's aligned-dwordx4 row engine
//     (1536B contiguous per row visit)
//   - double-buffered z (83KB) + out (62KB) LDS; __syncthreads per slot;
//     loads, sim, stores all concurrently in flight.
// fp16 staging accuracy proven R6-R13 (absmax 1.0 << threshold 4.94).

#define N_PATHS 100000
#define N_STEPS 512
#define TROW    1539               // (N_STEPS+1)*3 dwords per output row
#define PPG     40                 // paths per group
#define GPB     392                // paths per block
#define BT      192                // 3 waves
#define ZWRD    260                // zbuf row stride (f32): 256 data + 4 pad (16B-aligned rows)
#define OWRD    194                // obuf row stride (u32): 192 data + 2 pad
#define DTc     0.004f
#define EDT     1.0040080107f      // exp(DT)

typedef float  f32x4  __attribute__((ext_vector_type(4)));
typedef __fp16 fp16x2 __attribute__((ext_vector_type(2)));

__device__ __forceinline__ unsigned pk2(float a, float b) {
    union { fp16x2 h; unsigned u; } cv;
    cv.h = __builtin_amdgcn_cvt_pkrtz(a, b);
    return cv.u;
}
__device__ __forceinline__ float exlo(unsigned w) {
    return __half2float(__ushort_as_half((unsigned short)(w & 0xFFFFu)));
}
__device__ __forceinline__ float exhi(unsigned w) {
    return __half2float(__ushort_as_half((unsigned short)(w >> 16)));
}

__global__ __launch_bounds__(BT)
void heston_kernel(const float* __restrict__ z, float* __restrict__ out) {
    __shared__ float    zb[2][PPG * ZWRD];   // 83,200 B
    __shared__ unsigned ob[2][PPG * OWRD];   // 62,080 B  (total 145,280 -> 1 block/CU)

    const int tid = threadIdx.x;
    const int wv  = tid >> 6;     // 0: z-loader, 1: sim, 2: store
    const int ln  = tid & 63;
    const size_t pbase = (size_t)blockIdx.x * GPB;
    if (pbase >= N_PATHS) return;
    const int npath = (int)((N_PATHS - pbase < GPB) ? (N_PATHS - pbase) : GPB);
    const int ngrp  = (npath + PPG - 1) / PPG;    // 10 (block 255: 1)
    const int nslot = ngrp * 4;

    // sim state (wave 1 lanes; reset at each group's quarter 0)
    float s = 0.f, v = 0.f, acc = 0.f, tau = 0.f, e = 0.f;
    const float E0 = expf(-2.048f);

    for (int slot = 0; slot < nslot + 2; ++slot) {
        // ---------------- wave 0: load z for `slot` ----------------
        if (wv == 0 && slot < nslot) {
            const int g = slot >> 2, q = slot & 3;
            float* dst = zb[slot & 1];
            const size_t prow = pbase + (size_t)g * PPG;
            #pragma unroll 4
            for (int r = 0; r < PPG; ++r) {
                size_t pr = prow + r; if (pr > N_PATHS - 1) pr = N_PATHS - 1;
                const f32x4 d = *(const f32x4*)((const char*)z + pr * 4096 + q * 1024 + ln * 16);
                *(f32x4*)&dst[r * ZWRD + 4 * ln] = d;   // 1KB contiguous row visit
            }
        }

        // ---------------- wave 1: simulate `slot-1` ----------------
        if (wv == 1 && slot >= 1 && slot <= nslot) {
            const int s1 = slot - 1, q = s1 & 3;
            if (ln < PPG) {
                const float* src = zb[s1 & 1] + ln * ZWRD;
                unsigned*    dst = ob[s1 & 1] + ln * OWRD;
                if (q == 0) { s = 100.0f; v = 0.04f; acc = 0.04f; tau = 2.048f; e = E0; }
                float sP = 0.f, vP = 0.f, vsP = 0.f;
                #pragma unroll 8
                for (int d2 = 0; d2 < 64; ++d2) {        // 64 pairs = 128 steps
                    const f32x4 qz = *(const f32x4*)&src[4 * d2];  // 16B-aligned
                    #pragma unroll
                    for (int half = 0; half < 2; ++half) {
                        const float z0 = half ? qz.z : qz.x;
                        const float z1 = half ? qz.w : qz.y;
                        const float vp  = fmaxf(v, 0.0f);
                        const float sv  = __builtin_amdgcn_sqrtf(vp);
                        const float dW1 = 0.06324555320f * z0;                    // sqrt(DT)*z0
                        const float dW2 = fmaf(-0.7f, dW1, 0.04516636050f * z1);  // rho*dW1+c*sqrt(DT)*z1
                        s = fmaf(s * sv, dW1, s);
                        v = fmaxf(fmaf(0.2f * sv, dW2, fmaf(0.04f - vp, DTc, v)), 0.0f);
                        acc += v;
                        tau -= DTc;
                        e *= EDT;
                        const float vs = fmaf(acc, DTc, fmaf(0.04f, tau, (v - 0.04f) * (1.0f - e)));
                        if (half) {   // output-order words {s0,v0}{vs0,s1}{v1,vs1}
                            dst[3 * d2 + 0] = pk2(sP, vP);
                            dst[3 * d2 + 1] = pk2(vsP, s);
                            dst[3 * d2 + 2] = pk2(v, vs);
                        } else { sP = s; vP = v; vsP = vs; }
                    }
                }
            }
        }

        // ---------------- wave 2: store `slot-2` ----------------
        if (wv == 2 && slot >= 2) {
            const int s2 = slot - 2, g = s2 >> 2, q = s2 & 3;
            const unsigned* buf = ob[s2 & 1];
            const int j = ln;
            for (int r = 0; r < PPG; ++r) {
                const size_t prow = pbase + (size_t)g * PPG + r;
                const unsigned* lr = buf + r * OWRD;
                float* gr = out + prow * (size_t)TROW;

                if (q == 0 && j < 3)   // header
                    gr[j] = (j == 0) ? 100.0f : ((j == 1) ? 0.04f : 0.08208f);

                const size_t base = prow * (size_t)TROW + 3 + 384 * q;  // abs dword idx
                float* gq = gr + 3 + 384 * q;
                const int lead = (int)((0u - (unsigned)(base & 3u)) & 3u);
                const int ng   = (384 - lead) >> 2;
                const int tl   = (384 - lead) & 3;

                if (j < lead) {
                    const unsigned w = lr[j >> 1];
                    gq[j] = (j & 1) ? exhi(w) : exlo(w);
                }
                if (j < tl) {
                    const int idx = lead + 4 * ng + j;
                    const unsigned w = lr[idx >> 1];
                    gq[idx] = (idx & 1) ? exhi(w) : exlo(w);
                }
                const int sh = (lead & 1) * 16;
                #pragma unroll
                for (int k = 0; k < 2; ++k) {
                    const int gI = j + 64 * k;
                    if (gI < ng) {
                        const int idx = lead + 4 * gI;
                        const int w0  = idx >> 1;
                        const unsigned W0 = lr[w0];
                        const unsigned W1 = lr[w0 + 1];
                        const unsigned W2 = lr[w0 + 2];
                        const unsigned lo = __builtin_amdgcn_alignbit(W1, W0, sh);
                        const unsigned hi = __builtin_amdgcn_alignbit(W2, W1, sh);
                        f32x4 o;
                        o.x = exlo(lo); o.y = exhi(lo);
                        o.z = exlo(hi); o.w = exhi(hi);
                        *(f32x4*)(gq + lead + 4 * gI) = o;   // 16B-aligned dwordx4
                    }
                }
            }
        }

        __syncthreads();
    }
}

extern "C" void kernel_launch(void* const* d_in, const int* in_sizes, int n_in,
                              void* d_out, int out_size, void* d_ws, size_t ws_size,
                              hipStream_t stream) {
    const float* z = (const float*)d_in[0];
    float* out = (float*)d_out;
    heston_kernel<<<256, BT, 0, stream>>>(z, out);   // 256*392 = 100352 >= 100000
}

// Round 16
// 407.801 us; speedup vs baseline: 1.2369x; 1.2369x over previous
//
#include <hip/hip_runtime.h>
#include <hip/hip_fp16.h>

// Heston Euler-Maruyama: 100000 paths x 512 steps, fp32. Single kernel.
// R6/R9 proven structure + TRUE dwordx4 stores (alignbit row engine from R12):
//   - one wave per 64 paths, barrier-free; 4 phases x 128 steps
//   - z per-lane f32x4, depth-1 register prefetch (proven)
//   - outputs packed fp16 (cvt_pkrtz) into 49.9KB LDS tile -> 3 blocks/CU
//   - phase-end burst: per row 1536B; lead=(-(base&3))&3 edge dwords scalar,
//     body as 16B-ALIGNED f32x4 stores (compiler emits global_store_dwordx4)
//     with v_alignbit funnel shift for odd half-phase (validated in R12)
//   - OSTR=195 (odd): pack writes AND burst reads at free 2-way bank aliasing
// fp16 staging accuracy proven R6-R14 (absmax 1.0 << threshold 4.94).

#define N_PATHS 100000
#define N_STEPS 512
#define TROW    1539               // (N_STEPS+1)*3 dwords per output row
#define PB      64                 // paths per block = one wave
#define SUB     16                 // steps per z subchunk
#define NSUB    32                 // total subchunks
#define NPH     4                  // phases (128 steps each)
#define PHSUB   8                  // subchunks per phase
#define OSTR    195                // tile row stride in u32 (192 data + 3 pad, odd)
#define DTc     0.004f
#define EDT     1.0040080107f      // exp(DT)

typedef float  f32x4  __attribute__((ext_vector_type(4)));
typedef __fp16 fp16x2 __attribute__((ext_vector_type(2)));

__device__ __forceinline__ unsigned pk2(float a, float b) {
    union { fp16x2 h; unsigned u; } cv;
    cv.h = __builtin_amdgcn_cvt_pkrtz(a, b);   // v_cvt_pkrtz_f16_f32
    return cv.u;
}
__device__ __forceinline__ float exlo(unsigned w) {
    return __half2float(__ushort_as_half((unsigned short)(w & 0xFFFFu)));
}
__device__ __forceinline__ float exhi(unsigned w) {
    return __half2float(__ushort_as_half((unsigned short)(w >> 16)));
}

__global__ __launch_bounds__(PB)
void heston_kernel(const float* __restrict__ z, float* __restrict__ out) {
    __shared__ unsigned olB[PB * OSTR];   // 49,920 B -> 3 blocks/CU

    const int tid = threadIdx.x;
    const int p0  = blockIdx.x * PB;
    const int lim = N_PATHS - p0;
    const int limS = (lim >= PB) ? PB : lim;
    const int p   = p0 + tid;
    const int pc  = (p < N_PATHS) ? p : (N_PATHS - 1);   // clamp: no OOB reads

    const char* zp = (const char*)z + (size_t)pc * 4096;

    // prologue: subchunk 0 -> fA
    f32x4 fA[8], fB[8];
    #pragma unroll
    for (int j = 0; j < 8; ++j) fA[j] = *(const f32x4*)(zp + 16 * j);

    // t = 0 header
    {
        #pragma unroll
        for (int k = 0; k < 3; ++k) {
            int idx = k * PB + tid;
            int pl = idx / 3, si = idx - pl * 3;
            if (pl < lim)
                out[(size_t)(p0 + pl) * TROW + si] =
                    (si == 0) ? 100.0f : (si == 1) ? 0.04f : 0.08208f;
        }
    }

    float s = 100.0f, v = 0.04f, acc = 0.04f, tau = 2.048f, e = expf(-2.048f);
    float sP = 0.f, vP = 0.f, vsP = 0.f;      // even-step stash

    // one 16-step subchunk: prefetch sc+1 into nxt, compute from cur, pack->LDS
    auto doSub = [&](int sc, int su, f32x4 (&cur)[8], f32x4 (&nxt)[8]) {
        if (sc + 1 < NSUB) {
            const char* zc = zp + (size_t)(sc + 1) * 128;
            #pragma unroll
            for (int j = 0; j < 8; ++j) nxt[j] = *(const f32x4*)(zc + 16 * j);
        }
        const int dbase = tid * OSTR + su * 24;   // 24 u32 words per subchunk
        #pragma unroll
        for (int dt = 0; dt < SUB; ++dt) {
            const f32x4 q  = cur[dt >> 1];
            const float z0 = (dt & 1) ? q.z : q.x;
            const float z1 = (dt & 1) ? q.w : q.y;

            const float vp  = fmaxf(v, 0.0f);
            const float sv  = __builtin_amdgcn_sqrtf(vp);
            const float dW1 = 0.06324555320f * z0;                    // sqrt(DT)*z0
            const float dW2 = fmaf(-0.7f, dW1, 0.04516636050f * z1);  // rho*dW1 + c*sqrt(DT)*z1
            s = fmaf(s * sv, dW1, s);
            v = fmaxf(fmaf(0.2f * sv, dW2, fmaf(0.04f - vp, DTc, v)), 0.0f);
            acc += v;
            tau -= DTc;
            e *= EDT;
            const float vs = fmaf(acc, DTc, fmaf(0.04f, tau, (v - 0.04f) * (1.0f - e)));

            if (dt & 1) {   // words: {s0,v0} {vs0,s1} {v1,vs1}
                const int d = dbase + 3 * (dt >> 1);
                olB[d + 0] = pk2(sP, vP);
                olB[d + 1] = pk2(vsP, s);
                olB[d + 2] = pk2(v, vs);
            } else { sP = s; vP = v; vsP = vs; }
        }
    };

    for (int ph = 0; ph < NPH; ++ph) {
        const int sc0 = ph * PHSUB;
        doSub(sc0 + 0, 0, fA, fB);
        doSub(sc0 + 1, 1, fB, fA);
        doSub(sc0 + 2, 2, fA, fB);
        doSub(sc0 + 3, 3, fB, fA);
        doSub(sc0 + 4, 4, fA, fB);
        doSub(sc0 + 5, 5, fB, fA);
        doSub(sc0 + 6, 6, fA, fB);
        doSub(sc0 + 7, 7, fB, fA);
        // (last doSub prefetched next phase's first subchunk BEFORE the burst)

        // ---- burst: per row 1536B with TRUE 16B-aligned dwordx4 body ----
        for (int pl = 0; pl < limS; ++pl) {
            const unsigned* lr = &olB[pl * OSTR];          // 384 data halfs
            const size_t base = (size_t)(p0 + pl) * TROW + 3 + (size_t)ph * 384;
            float* gr = out + base;
            const int lead = (int)((0u - (unsigned)(base & 3u)) & 3u);
            const int ng   = (384 - lead) >> 2;            // full x4 groups
            const int tl   = (384 - lead) & 3;

            if (tid < lead) {                              // lead edge (<4 dwords)
                const unsigned w = lr[tid >> 1];
                gr[tid] = (tid & 1) ? exhi(w) : exlo(w);
            }
            if (tid < tl) {                                // tail edge (<4 dwords)
                const int idx = lead + 4 * ng + tid;
                const unsigned w = lr[idx >> 1];
                gr[idx] = (idx & 1) ? exhi(w) : exlo(w);
            }

            const int sh = (lead & 1) * 16;                // row-uniform funnel shift
            #pragma unroll
            for (int k = 0; k < 2; ++k) {
                const int g = tid + 64 * k;
                if (g < ng) {
                    const int idx = lead + 4 * g;          // starting half index
                    const int w0  = idx >> 1;
                    const unsigned W0 = lr[w0];
                    const unsigned W1 = lr[w0 + 1];
                    const unsigned W2 = lr[w0 + 2];
                    const unsigned lo = __builtin_amdgcn_alignbit(W1, W0, sh);
                    const unsigned hi = __builtin_amdgcn_alignbit(W2, W1, sh);
                    f32x4 o;
                    o.x = exlo(lo); o.y = exhi(lo);
                    o.z = exlo(hi); o.w = exhi(hi);
                    *(f32x4*)(gr + lead + 4 * g) = o;      // provably 16B-aligned
                }
            }
        }
    }
}

extern "C" void kernel_launch(void* const* d_in, const int* in_sizes, int n_in,
                              void* d_out, int out_size, void* d_ws, size_t ws_size,
                              hipStream_t stream) {
    const float* z = (const float*)d_in[0];
    float* out = (float*)d_out;
    const int nblocks = (N_PATHS + PB - 1) / PB;   // 1563
    heston_kernel<<<nblocks, PB, 0, stream>>>(z, out);
}

// Round 17
// 312.060 us; speedup vs baseline: 1.6164x; 1.3068x over previous
//
#include <hip/hip_runtime.h>
#include <hip/hip_fp16.h>

// Heston Euler-Maruyama: 100000 paths x 512 steps, fp32. Single kernel.
// R6 (best: 309.8us) byte-identical EXCEPT output stores are NON-TEMPORAL
// (MUBUF `nt` flag -> bypass L2 write-allocate/RMW path). Single-variable
// experiment: if L2 write-path stalls were the ~2.5 TB/s throttle, this
// moves; if not, R6's 310us is the practical ceiling.
//   - one wave per 64 paths, barrier-free; 4 phases x 128 steps
//   - z per-lane f32x4, depth-1 register prefetch
//   - outputs packed fp16 (cvt_pkrtz) into 49.4KB LDS tile -> 3 blocks/CU
//   - phase-end burst: expand fp16->fp32, 1536B/row as 6 x 256B dword
//     store instructions, all nontemporal
// fp16 staging accuracy proven R6-R15 (absmax 1.0 << threshold 4.94).

#define N_PATHS 100000
#define N_STEPS 512
#define TROW    1539               // (N_STEPS+1)*3 dwords per output row
#define PB      64                 // paths per block = one wave
#define SUB     16                 // steps per z subchunk
#define NSUB    32                 // total subchunks
#define NPH     4                  // phases (128 steps each)
#define PHSUB   8                  // subchunks per phase
#define OSTR    193                // tile row stride in u32 (192 data + 1 pad, odd)
#define DTc     0.004f
#define EDT     1.0040080107f      // exp(DT)

typedef float  f32x4  __attribute__((ext_vector_type(4)));
typedef __fp16 fp16x2 __attribute__((ext_vector_type(2)));

__device__ __forceinline__ unsigned pk2(float a, float b) {
    union { fp16x2 h; unsigned u; } cv;
    cv.h = __builtin_amdgcn_cvt_pkrtz(a, b);   // v_cvt_pkrtz_f16_f32
    return cv.u;
}

__device__ __forceinline__ float ex16(unsigned w, int h) {
    const unsigned us = h ? (w >> 16) : (w & 0xFFFFu);
    return __half2float(__ushort_as_half((unsigned short)us));
}

__global__ __launch_bounds__(PB)
void heston_kernel(const float* __restrict__ z, float* __restrict__ out) {
    __shared__ unsigned olB[PB * OSTR];   // 49.4 KB -> 3 blocks/CU

    const int tid = threadIdx.x;
    const int p0  = blockIdx.x * PB;
    const int lim = N_PATHS - p0;
    const int limS = (lim >= PB) ? PB : lim;
    const int p   = p0 + tid;
    const int pc  = (p < N_PATHS) ? p : (N_PATHS - 1);   // clamp: no OOB reads

    const char* zp = (const char*)z + (size_t)pc * 4096;

    // prologue: subchunk 0 -> fA
    f32x4 fA[8], fB[8];
    #pragma unroll
    for (int j = 0; j < 8; ++j) fA[j] = *(const f32x4*)(zp + 16 * j);

    // t = 0 header
    {
        #pragma unroll
        for (int k = 0; k < 3; ++k) {
            int idx = k * PB + tid;
            int pl = idx / 3, si = idx - pl * 3;
            if (pl < lim) {
                const float val = (si == 0) ? 100.0f : (si == 1) ? 0.04f : 0.08208f;
                __builtin_nontemporal_store(val, &out[(size_t)(p0 + pl) * TROW + si]);
            }
        }
    }

    float s = 100.0f, v = 0.04f, acc = 0.04f, tau = 2.048f, e = expf(-2.048f);
    float sP = 0.f, vP = 0.f, vsP = 0.f;      // even-step stash

    // one 16-step subchunk: prefetch sc+1 into nxt, compute from cur, pack->LDS
    auto doSub = [&](int sc, int su, f32x4 (&cur)[8], f32x4 (&nxt)[8]) {
        if (sc + 1 < NSUB) {
            const char* zc = zp + (size_t)(sc + 1) * 128;
            #pragma unroll
            for (int j = 0; j < 8; ++j) nxt[j] = *(const f32x4*)(zc + 16 * j);
        }
        const int dbase = tid * OSTR + su * 24;   // 24 u32 words per subchunk
        #pragma unroll
        for (int dt = 0; dt < SUB; ++dt) {
            const f32x4 q  = cur[dt >> 1];
            const float z0 = (dt & 1) ? q.z : q.x;
            const float z1 = (dt & 1) ? q.w : q.y;

            const float vp  = fmaxf(v, 0.0f);
            const float sv  = __builtin_amdgcn_sqrtf(vp);
            const float dW1 = 0.06324555320f * z0;                    // sqrt(DT)*z0
            const float dW2 = fmaf(-0.7f, dW1, 0.04516636050f * z1);  // rho*dW1 + c*sqrt(DT)*z1
            s = fmaf(s * sv, dW1, s);
            v = fmaxf(fmaf(0.2f * sv, dW2, fmaf(0.04f - vp, DTc, v)), 0.0f);
            acc += v;
            tau -= DTc;
            e *= EDT;
            const float vs = fmaf(acc, DTc, fmaf(0.04f, tau, (v - 0.04f) * (1.0f - e)));

            if (dt & 1) {   // words: {s0,v0} {vs0,s1} {v1,vs1}
                const int d = dbase + 3 * (dt >> 1);
                olB[d + 0] = pk2(sP, vP);
                olB[d + 1] = pk2(vsP, s);
                olB[d + 2] = pk2(v, vs);
            } else { sP = s; vP = v; vsP = vs; }
        }
    };

    const int h  = tid & 1;    // which half of the u32
    const int tq = tid >> 1;   // lane pairs broadcast-read the same word (free)

    for (int ph = 0; ph < NPH; ++ph) {
        const int sc0 = ph * PHSUB;
        doSub(sc0 + 0, 0, fA, fB);
        doSub(sc0 + 1, 1, fB, fA);
        doSub(sc0 + 2, 2, fA, fB);
        doSub(sc0 + 3, 3, fB, fA);
        doSub(sc0 + 4, 4, fA, fB);
        doSub(sc0 + 5, 5, fB, fA);
        doSub(sc0 + 6, 6, fA, fB);
        doSub(sc0 + 7, 7, fB, fA);
        // (last doSub prefetched next phase's first subchunk BEFORE the burst)

        // dense store burst: limS rows x 1536B, each row = 6 back-to-back
        // 256B-contiguous NONTEMPORAL dword stores (fp16 -> fp32 expand)
        float* gp = out + (size_t)p0 * TROW + 3 + ph * 384;
        if (limS == PB) {
            for (int pl = 0; pl < PB; ++pl) {
                const unsigned* lw = &olB[pl * OSTR + tq];
                float* gr = gp + (size_t)pl * TROW + tid;
                #pragma unroll
                for (int k = 0; k < 6; ++k) {
                    __builtin_nontemporal_store(ex16(lw[32 * k], h), &gr[64 * k]);
                }
            }
        } else {
            for (int pl = 0; pl < limS; ++pl) {
                const unsigned* lw = &olB[pl * OSTR + tq];
                float* gr = gp + (size_t)pl * TROW + tid;
                #pragma unroll
                for (int k = 0; k < 6; ++k) {
                    __builtin_nontemporal_store(ex16(lw[32 * k], h), &gr[64 * k]);
                }
            }
        }
    }
}

extern "C" void kernel_launch(void* const* d_in, const int* in_sizes, int n_in,
                              void* d_out, int out_size, void* d_ws, size_t ws_size,
                              hipStream_t stream) {
    const float* z = (const float*)d_in[0];
    float* out = (float*)d_out;
    const int nblocks = (N_PATHS + PB - 1) / PB;   // 1563
    heston_kernel<<<nblocks, PB, 0, stream>>>(z, out);
}